// Round 3
// baseline (461.284 us; speedup 1.0000x reference)
//
#include <hip/hip_runtime.h>
#include <hip/hip_bf16.h>

typedef __attribute__((ext_vector_type(8))) __bf16 bf16x8;
typedef __attribute__((ext_vector_type(4))) float f32x4;

#define F_DIM 512
#define D_DIM 128
#define SCAN_CHUNK 2048   // 256 threads x 8 elems

__device__ __forceinline__ unsigned short f32_to_bf16_rn(float x) {
    union { float f; unsigned u; } v; v.f = x;
    unsigned u = v.u;
    unsigned rounded = u + 0x7fffu + ((u >> 16) & 1u);
    return (unsigned short)(rounded >> 16);
}

// W [512][128] f32 -> Wt [128][512] bf16 (transposed, k-contiguous)
__global__ void wt_kernel(const float* __restrict__ W, unsigned short* __restrict__ Wt) {
    int idx = blockIdx.x * blockDim.x + threadIdx.x;   // 65536 total
    int n = idx >> 9;
    int k = idx & 511;
    Wt[idx] = f32_to_bf16_rn(W[k * D_DIM + n]);
}

__device__ __forceinline__ bf16x8 cvt8(float4 a, float4 b) {
    union { bf16x8 v; unsigned short u[8]; } r;
    r.u[0] = f32_to_bf16_rn(a.x); r.u[1] = f32_to_bf16_rn(a.y);
    r.u[2] = f32_to_bf16_rn(a.z); r.u[3] = f32_to_bf16_rn(a.w);
    r.u[4] = f32_to_bf16_rn(b.x); r.u[5] = f32_to_bf16_rn(b.y);
    r.u[6] = f32_to_bf16_rn(b.z); r.u[7] = f32_to_bf16_rn(b.w);
    return r.v;
}

// LDS-free GEMM: one wave = 16 output rows x 128 cols. A from global (fp32,
// converted in-reg), B from L2-resident Wt (128 KB). No barriers at all.
__global__ __launch_bounds__(256) void gemm_relu_direct(
    const float* __restrict__ A,
    const unsigned short* __restrict__ Bt,
    float* __restrict__ S,
    int Nrows)
{
    const int wid  = (blockIdx.x * 256 + threadIdx.x) >> 6;
    const int lane = threadIdx.x & 63;
    const int r16  = lane & 15;
    const int g    = lane >> 4;       // k-group 0..3
    const int m0   = wid * 16;
    if (m0 >= Nrows) return;

    int arow_idx = m0 + r16;
    if (arow_idx >= Nrows) arow_idx = Nrows - 1;   // safe duplicate, output guarded
    const float* arow = A + (size_t)arow_idx * F_DIM;

    f32x4 acc[8];
#pragma unroll
    for (int nf = 0; nf < 8; ++nf) acc[nf] = (f32x4)0.0f;

#pragma unroll 2
    for (int ks = 0; ks < 16; ++ks) {
        const int k0 = ks * 32 + g * 8;
        float4 a0 = *(const float4*)&arow[k0];
        float4 a1 = *(const float4*)&arow[k0 + 4];
        bf16x8 af = cvt8(a0, a1);
#pragma unroll
        for (int nf = 0; nf < 8; ++nf) {
            bf16x8 bf = *(const bf16x8*)&Bt[(size_t)(nf * 16 + r16) * F_DIM + k0];
            acc[nf] = __builtin_amdgcn_mfma_f32_16x16x32_bf16(af, bf, acc[nf], 0, 0, 0);
        }
    }

#pragma unroll
    for (int nf = 0; nf < 8; ++nf) {
#pragma unroll
        for (int r = 0; r < 4; ++r) {
            int orow = m0 + g * 4 + r;
            if (orow < Nrows) {
                float v = acc[nf][r];
                S[(size_t)orow * D_DIM + nf * 16 + r16] = v > 0.f ? v : 0.f;
            }
        }
    }
}

// ---- CSR build ----

__global__ void hist_kernel(const int* __restrict__ ei, int* __restrict__ counts, int E) {
    int e = blockIdx.x * blockDim.x + threadIdx.x;
    if (e < E) atomicAdd(&counts[ei[e]], 1);
}

// per-chunk exclusive scan (256 threads x 8 elems), block sums out
__global__ __launch_bounds__(256) void scan1_kernel(const int* __restrict__ counts,
                                                    int* __restrict__ offsets,
                                                    int* __restrict__ bsum, int n) {
    __shared__ int tsum[256];
    int base = blockIdx.x * SCAN_CHUNK;
    int t = threadIdx.x;
    int local[8];
    int s = 0;
#pragma unroll
    for (int j = 0; j < 8; ++j) {
        int idx = base + t * 8 + j;
        int c = (idx < n) ? counts[idx] : 0;
        local[j] = s;
        s += c;
    }
    tsum[t] = s;
    __syncthreads();
    for (int d = 1; d < 256; d <<= 1) {
        int v = (t >= d) ? tsum[t - d] : 0;
        __syncthreads();
        if (t >= d) tsum[t] += v;
        __syncthreads();
    }
    int texcl = (t > 0) ? tsum[t - 1] : 0;
#pragma unroll
    for (int j = 0; j < 8; ++j) {
        int idx = base + t * 8 + j;
        if (idx < n) offsets[idx] = texcl + local[j];
    }
    if (t == 255) bsum[blockIdx.x] = tsum[255];
}

// single-wave generic scan of block sums (nb arbitrary, 64-wide chunks + carry)
__global__ void scan2_kernel(const int* __restrict__ bsum, int* __restrict__ bscan, int nb) {
    int lane = threadIdx.x;   // launched with 64
    int carry = 0;
    for (int base = 0; base < nb; base += 64) {
        int idx = base + lane;
        int v = (idx < nb) ? bsum[idx] : 0;
        int orig = v;
        for (int d = 1; d < 64; d <<= 1) {
            int t = __shfl_up(v, d, 64);
            if (lane >= d) v += t;
        }
        if (idx < nb) bscan[idx] = carry + v - orig;
        carry += __shfl(v, 63, 64);
    }
}

__global__ void scan3_kernel(int* __restrict__ offsets, const int* __restrict__ bscan,
                             int n, int Etot) {
    int i = blockIdx.x * blockDim.x + threadIdx.x;
    if (i < n) offsets[i] += bscan[i / SCAN_CHUNK];
    else if (i == n) offsets[n] = Etot;
}

// scatter edges into CSR order: ecv[p] = {col, val}
__global__ void reorder_kernel(const int* __restrict__ ei, const float* __restrict__ ev,
                               int* __restrict__ cursor, uint2* __restrict__ ecv, int E) {
    int e = blockIdx.x * blockDim.x + threadIdx.x;
    if (e >= E) return;
    int r = ei[e];
    int p = atomicAdd(&cursor[r], 1);
    uint2 cv;
    cv.x = (unsigned)ei[E + e];
    cv.y = __float_as_uint(ev[e]);
    ecv[p] = cv;
}

// one wave per row: acc = sum(val * S[col]); out = acc + S[row] + bias
// 4-deep unroll for gather MLP.
__global__ __launch_bounds__(256) void accum_kernel(
    const uint2* __restrict__ ecv, const int* __restrict__ offsets,
    const float* __restrict__ S, const float* __restrict__ bias,
    float* __restrict__ out, int n)
{
    int wid = (blockIdx.x * 256 + threadIdx.x) >> 6;
    if (wid >= n) return;
    int lane = threadIdx.x & 63;
    int c2 = lane * 2;

    int start = offsets[wid];
    int end   = offsets[wid + 1];

    float ax = 0.f, ay = 0.f;
    int i = start;
    for (; i + 3 < end; i += 4) {
        uint2 cv0 = ecv[i];
        uint2 cv1 = ecv[i + 1];
        uint2 cv2 = ecv[i + 2];
        uint2 cv3 = ecv[i + 3];
        float2 s0 = *(const float2*)&S[(size_t)cv0.x * D_DIM + c2];
        float2 s1 = *(const float2*)&S[(size_t)cv1.x * D_DIM + c2];
        float2 s2 = *(const float2*)&S[(size_t)cv2.x * D_DIM + c2];
        float2 s3 = *(const float2*)&S[(size_t)cv3.x * D_DIM + c2];
        float v0 = __uint_as_float(cv0.y);
        float v1 = __uint_as_float(cv1.y);
        float v2 = __uint_as_float(cv2.y);
        float v3 = __uint_as_float(cv3.y);
        ax += v0 * s0.x + v1 * s1.x + v2 * s2.x + v3 * s3.x;
        ay += v0 * s0.y + v1 * s1.y + v2 * s2.y + v3 * s3.y;
    }
    for (; i < end; ++i) {
        uint2 cv = ecv[i];
        float2 s = *(const float2*)&S[(size_t)cv.x * D_DIM + c2];
        float v = __uint_as_float(cv.y);
        ax += v * s.x;
        ay += v * s.y;
    }

    float2 own = *(const float2*)&S[(size_t)wid * D_DIM + c2];
    float2 b   = *(const float2*)&bias[c2];
    float2 o;
    o.x = ax + own.x + b.x;
    o.y = ay + own.y + b.y;
    *(float2*)&out[(size_t)wid * D_DIM + c2] = o;
}

extern "C" void kernel_launch(void* const* d_in, const int* in_sizes, int n_in,
                              void* d_out, int out_size, void* d_ws, size_t ws_size,
                              hipStream_t stream) {
    const float* feature = (const float*)d_in[0];
    const float* W       = (const float*)d_in[1];
    const float* bias    = (const float*)d_in[2];
    const float* ev      = (const float*)d_in[3];
    const int*   ei      = (const int*)d_in[4];
    float* out = (float*)d_out;

    const int N = in_sizes[0] / F_DIM;   // 100000
    const int E = in_sizes[3];           // 1600000
    const int NB = (N + SCAN_CHUNK - 1) / SCAN_CHUNK;

    // workspace layout (256B aligned slabs)
    char* ws = (char*)d_ws;
    size_t cur = 0;
    auto alloc = [&](size_t bytes) -> void* {
        void* p = ws + cur;
        cur = (cur + bytes + 255) & ~(size_t)255;
        return p;
    };
    float*          S       = (float*)alloc((size_t)N * D_DIM * 4);
    unsigned short* Wt      = (unsigned short*)alloc((size_t)D_DIM * F_DIM * 2);
    int*            counts  = (int*)alloc((size_t)N * 4);
    int*            offsets = (int*)alloc((size_t)(N + 1) * 4);
    int*            bsum    = (int*)alloc((size_t)NB * 4);
    int*            bscan   = (int*)alloc((size_t)NB * 4);
    int*            cursor  = (int*)alloc((size_t)N * 4);
    uint2*          ecv     = (uint2*)alloc((size_t)E * 8);
    (void)ws_size;

    // GEMM path
    wt_kernel<<<(F_DIM * D_DIM) / 256, 256, 0, stream>>>(W, Wt);
    {
        int waves  = (N + 15) / 16;
        int blocks = (waves + 3) / 4;
        gemm_relu_direct<<<blocks, 256, 0, stream>>>(feature, Wt, S, N);
    }

    // CSR build
    hipMemsetAsync(counts, 0, (size_t)N * 4, stream);
    hist_kernel<<<(E + 255) / 256, 256, 0, stream>>>(ei, counts, E);
    scan1_kernel<<<NB, 256, 0, stream>>>(counts, offsets, bsum, N);
    scan2_kernel<<<1, 64, 0, stream>>>(bsum, bscan, NB);
    scan3_kernel<<<(N + 1 + 255) / 256, 256, 0, stream>>>(offsets, bscan, N, E);
    hipMemcpyAsync(cursor, offsets, (size_t)N * 4, hipMemcpyDeviceToDevice, stream);
    reorder_kernel<<<(E + 255) / 256, 256, 0, stream>>>(ei, ev, cursor, ecv, E);

    // atomic-free accumulate + identity + bias
    accum_kernel<<<(N + 3) / 4, 256, 0, stream>>>(ecv, offsets, S, bias, out, N);
}

// Round 4
// 395.196 us; speedup vs baseline: 1.1672x; 1.1672x over previous
//
#include <hip/hip_runtime.h>
#include <hip/hip_bf16.h>

typedef __attribute__((ext_vector_type(8))) __bf16 bf16x8;
typedef __attribute__((ext_vector_type(4))) float f32x4;

#define F_DIM 512
#define D_DIM 128
#define SCAN_CHUNK 2048   // 256 threads x 8 elems

__device__ __forceinline__ unsigned short f32_to_bf16_rn(float x) {
    union { float f; unsigned u; } v; v.f = x;
    unsigned u = v.u;
    unsigned rounded = u + 0x7fffu + ((u >> 16) & 1u);
    return (unsigned short)(rounded >> 16);
}

// W [512][128] f32 -> Wt [128][512] bf16 (transposed, k-contiguous)
__global__ void wt_kernel(const float* __restrict__ W, unsigned short* __restrict__ Wt) {
    int idx = blockIdx.x * blockDim.x + threadIdx.x;   // 65536 total
    int n = idx >> 9;
    int k = idx & 511;
    Wt[idx] = f32_to_bf16_rn(W[k * D_DIM + n]);
}

// support = relu(feature @ W). 128(M)x128(N) block tile, BK=32, 4 waves.
// Reg-staged + LDS double-buffer, ONE barrier per K-step. A converted to bf16
// in-reg via (__bf16) casts (packed cvt).
__global__ __launch_bounds__(256) void gemm_relu_pipe(
    const float* __restrict__ A,
    const unsigned short* __restrict__ Bt,
    float* __restrict__ S,
    int Nrows)
{
    __shared__ unsigned short Al[2 * 128 * 40];  // [buf][row][k] padded stride 40
    __shared__ unsigned short Bl[2 * 128 * 40];

    const int tid  = threadIdx.x;
    const int wave = tid >> 6;
    const int lane = tid & 63;
    const int g    = lane >> 4;
    const int r16  = lane & 15;
    const int m0   = blockIdx.x * 128;

    // staging role: thread covers row srow, k-half kh (16 floats)
    const int srow = tid >> 1;
    const int kh   = tid & 1;
    int arow = m0 + srow;
    if (arow >= Nrows) arow = Nrows - 1;           // duplicate-safe; stores guarded
    const float*          aptr = A  + (size_t)arow * F_DIM + kh * 16;
    const unsigned short* bptr = Bt + (size_t)srow * F_DIM + kh * 16;
    const int woff = srow * 40 + kh * 16;

    float4 ar0, ar1, ar2, ar3;
    uint4  br0, br1;

    auto loadAB = [&](int ks) {
        const float4* pa = (const float4*)(aptr + ks * 32);
        ar0 = pa[0]; ar1 = pa[1]; ar2 = pa[2]; ar3 = pa[3];
        const uint4* pb = (const uint4*)(bptr + ks * 32);
        br0 = pb[0]; br1 = pb[1];
    };
    auto storeAB = [&](int buf) {
        union { uint4 q[2]; __bf16 h[16]; } u;
        u.h[0]=(__bf16)ar0.x;  u.h[1]=(__bf16)ar0.y;  u.h[2]=(__bf16)ar0.z;  u.h[3]=(__bf16)ar0.w;
        u.h[4]=(__bf16)ar1.x;  u.h[5]=(__bf16)ar1.y;  u.h[6]=(__bf16)ar1.z;  u.h[7]=(__bf16)ar1.w;
        u.h[8]=(__bf16)ar2.x;  u.h[9]=(__bf16)ar2.y;  u.h[10]=(__bf16)ar2.z; u.h[11]=(__bf16)ar2.w;
        u.h[12]=(__bf16)ar3.x; u.h[13]=(__bf16)ar3.y; u.h[14]=(__bf16)ar3.z; u.h[15]=(__bf16)ar3.w;
        unsigned short* aw = Al + buf * 5120 + woff;
        unsigned short* bw = Bl + buf * 5120 + woff;
        *(uint4*)aw       = u.q[0];
        *(uint4*)(aw + 8) = u.q[1];
        *(uint4*)bw       = br0;
        *(uint4*)(bw + 8) = br1;
    };

    f32x4 acc[2][8];
#pragma unroll
    for (int i = 0; i < 2; ++i)
#pragma unroll
        for (int j = 0; j < 8; ++j) acc[i][j] = (f32x4)0.0f;

    // prologue: fill buf 0
    loadAB(0);
    storeAB(0);
    __syncthreads();

#pragma unroll
    for (int ks = 0; ks < 16; ++ks) {
        const int cur = ks & 1;
        if (ks < 15) loadAB(ks + 1);               // overlap with compute below

        const unsigned short* Ab = Al + cur * 5120;
        const unsigned short* Bb = Bl + cur * 5120;
        bf16x8 af0 = *(const bf16x8*)&Ab[(wave * 32 +      r16) * 40 + g * 8];
        bf16x8 af1 = *(const bf16x8*)&Ab[(wave * 32 + 16 + r16) * 40 + g * 8];
#pragma unroll
        for (int nf = 0; nf < 8; ++nf) {
            bf16x8 bf = *(const bf16x8*)&Bb[(nf * 16 + r16) * 40 + g * 8];
            acc[0][nf] = __builtin_amdgcn_mfma_f32_16x16x32_bf16(af0, bf, acc[0][nf], 0, 0, 0);
            acc[1][nf] = __builtin_amdgcn_mfma_f32_16x16x32_bf16(af1, bf, acc[1][nf], 0, 0, 0);
        }

        if (ks < 15) storeAB(cur ^ 1);             // write NEXT buf; waits on loads
        __syncthreads();
    }

    // epilogue: relu + store
#pragma unroll
    for (int mf = 0; mf < 2; ++mf) {
#pragma unroll
        for (int nf = 0; nf < 8; ++nf) {
#pragma unroll
            for (int r = 0; r < 4; ++r) {
                int row = m0 + wave * 32 + mf * 16 + g * 4 + r;
                if (row < Nrows) {
                    float v = acc[mf][nf][r];
                    S[(size_t)row * D_DIM + nf * 16 + r16] = v > 0.f ? v : 0.f;
                }
            }
        }
    }
}

// ---- CSR build ----

__global__ void hist_kernel(const int* __restrict__ ei, int* __restrict__ counts, int E) {
    int e = blockIdx.x * blockDim.x + threadIdx.x;
    if (e < E) atomicAdd(&counts[ei[e]], 1);
}

__global__ __launch_bounds__(256) void scan1_kernel(const int* __restrict__ counts,
                                                    int* __restrict__ offsets,
                                                    int* __restrict__ bsum, int n) {
    __shared__ int tsum[256];
    int base = blockIdx.x * SCAN_CHUNK;
    int t = threadIdx.x;
    int local[8];
    int s = 0;
#pragma unroll
    for (int j = 0; j < 8; ++j) {
        int idx = base + t * 8 + j;
        int c = (idx < n) ? counts[idx] : 0;
        local[j] = s;
        s += c;
    }
    tsum[t] = s;
    __syncthreads();
    for (int d = 1; d < 256; d <<= 1) {
        int v = (t >= d) ? tsum[t - d] : 0;
        __syncthreads();
        if (t >= d) tsum[t] += v;
        __syncthreads();
    }
    int texcl = (t > 0) ? tsum[t - 1] : 0;
#pragma unroll
    for (int j = 0; j < 8; ++j) {
        int idx = base + t * 8 + j;
        if (idx < n) offsets[idx] = texcl + local[j];
    }
    if (t == 255) bsum[blockIdx.x] = tsum[255];
}

// single-wave scan of block sums (64-wide chunks + running carry)
__global__ void scan2_kernel(const int* __restrict__ bsum, int* __restrict__ bscan, int nb) {
    int lane = threadIdx.x;   // launched with 64
    int carry = 0;
    for (int base = 0; base < nb; base += 64) {
        int idx = base + lane;
        int v = (idx < nb) ? bsum[idx] : 0;
        int orig = v;
        for (int d = 1; d < 64; d <<= 1) {
            int t = __shfl_up(v, d, 64);
            if (lane >= d) v += t;
        }
        if (idx < nb) bscan[idx] = carry + v - orig;
        carry += __shfl(v, 63, 64);
    }
}

__global__ void scan3_kernel(int* __restrict__ offsets, const int* __restrict__ bscan,
                             int n, int Etot) {
    int i = blockIdx.x * blockDim.x + threadIdx.x;
    if (i < n) offsets[i] += bscan[i / SCAN_CHUNK];
    else if (i == n) offsets[n] = Etot;
}

// scatter edges into CSR order: ecv[p] = {col, val}
__global__ void reorder_kernel(const int* __restrict__ ei, const float* __restrict__ ev,
                               int* __restrict__ cursor, uint2* __restrict__ ecv, int E) {
    int e = blockIdx.x * blockDim.x + threadIdx.x;
    if (e >= E) return;
    int r = ei[e];
    int p = atomicAdd(&cursor[r], 1);
    uint2 cv;
    cv.x = (unsigned)ei[E + e];
    cv.y = __float_as_uint(ev[e]);
    ecv[p] = cv;
}

// one wave per row: acc = sum(val * S[col]); out = acc + S[row] + bias
__global__ __launch_bounds__(256) void accum_kernel(
    const uint2* __restrict__ ecv, const int* __restrict__ offsets,
    const float* __restrict__ S, const float* __restrict__ bias,
    float* __restrict__ out, int n)
{
    int wid = (blockIdx.x * 256 + threadIdx.x) >> 6;
    if (wid >= n) return;
    int lane = threadIdx.x & 63;
    int c2 = lane * 2;

    int start = offsets[wid];
    int end   = offsets[wid + 1];

    float ax = 0.f, ay = 0.f;
    int i = start;
    for (; i + 3 < end; i += 4) {
        uint2 cv0 = ecv[i];
        uint2 cv1 = ecv[i + 1];
        uint2 cv2 = ecv[i + 2];
        uint2 cv3 = ecv[i + 3];
        float2 s0 = *(const float2*)&S[(size_t)cv0.x * D_DIM + c2];
        float2 s1 = *(const float2*)&S[(size_t)cv1.x * D_DIM + c2];
        float2 s2 = *(const float2*)&S[(size_t)cv2.x * D_DIM + c2];
        float2 s3 = *(const float2*)&S[(size_t)cv3.x * D_DIM + c2];
        float v0 = __uint_as_float(cv0.y);
        float v1 = __uint_as_float(cv1.y);
        float v2 = __uint_as_float(cv2.y);
        float v3 = __uint_as_float(cv3.y);
        ax += v0 * s0.x + v1 * s1.x + v2 * s2.x + v3 * s3.x;
        ay += v0 * s0.y + v1 * s1.y + v2 * s2.y + v3 * s3.y;
    }
    for (; i < end; ++i) {
        uint2 cv = ecv[i];
        float2 s = *(const float2*)&S[(size_t)cv.x * D_DIM + c2];
        float v = __uint_as_float(cv.y);
        ax += v * s.x;
        ay += v * s.y;
    }

    float2 own = *(const float2*)&S[(size_t)wid * D_DIM + c2];
    float2 b   = *(const float2*)&bias[c2];
    float2 o;
    o.x = ax + own.x + b.x;
    o.y = ay + own.y + b.y;
    *(float2*)&out[(size_t)wid * D_DIM + c2] = o;
}

extern "C" void kernel_launch(void* const* d_in, const int* in_sizes, int n_in,
                              void* d_out, int out_size, void* d_ws, size_t ws_size,
                              hipStream_t stream) {
    const float* feature = (const float*)d_in[0];
    const float* W       = (const float*)d_in[1];
    const float* bias    = (const float*)d_in[2];
    const float* ev      = (const float*)d_in[3];
    const int*   ei      = (const int*)d_in[4];
    float* out = (float*)d_out;

    const int N = in_sizes[0] / F_DIM;   // 100000
    const int E = in_sizes[3];           // 1600000
    const int NB = (N + SCAN_CHUNK - 1) / SCAN_CHUNK;

    char* ws = (char*)d_ws;
    size_t cur = 0;
    auto alloc = [&](size_t bytes) -> void* {
        void* p = ws + cur;
        cur = (cur + bytes + 255) & ~(size_t)255;
        return p;
    };
    float*          S       = (float*)alloc((size_t)N * D_DIM * 4);
    unsigned short* Wt      = (unsigned short*)alloc((size_t)D_DIM * F_DIM * 2);
    int*            counts  = (int*)alloc((size_t)N * 4);
    int*            offsets = (int*)alloc((size_t)(N + 1) * 4);
    int*            bsum    = (int*)alloc((size_t)NB * 4);
    int*            bscan   = (int*)alloc((size_t)NB * 4);
    int*            cursor  = (int*)alloc((size_t)N * 4);
    uint2*          ecv     = (uint2*)alloc((size_t)E * 8);
    (void)ws_size;

    // GEMM path
    wt_kernel<<<(F_DIM * D_DIM) / 256, 256, 0, stream>>>(W, Wt);
    gemm_relu_pipe<<<(N + 127) / 128, 256, 0, stream>>>(feature, Wt, S, N);

    // CSR build
    hipMemsetAsync(counts, 0, (size_t)N * 4, stream);
    hist_kernel<<<(E + 255) / 256, 256, 0, stream>>>(ei, counts, E);
    scan1_kernel<<<NB, 256, 0, stream>>>(counts, offsets, bsum, N);
    scan2_kernel<<<1, 64, 0, stream>>>(bsum, bscan, NB);
    scan3_kernel<<<(N + 1 + 255) / 256, 256, 0, stream>>>(offsets, bscan, N, E);
    hipMemcpyAsync(cursor, offsets, (size_t)N * 4, hipMemcpyDeviceToDevice, stream);
    reorder_kernel<<<(E + 255) / 256, 256, 0, stream>>>(ei, ev, cursor, ecv, E);

    // atomic-free accumulate + identity + bias
    accum_kernel<<<(N + 3) / 4, 256, 0, stream>>>(ecv, offsets, S, bias, out, N);
}